// Round 5
// baseline (276.378 us; speedup 1.0000x reference)
//
#include <hip/hip_runtime.h>
#include <hip/hip_bf16.h>

#define NB 32768
#define ND 512
#define NS 128
#define NE 8

typedef __attribute__((ext_vector_type(8))) short bf16x8;
typedef __attribute__((ext_vector_type(8))) unsigned short u16x8;
typedef __attribute__((ext_vector_type(4))) float f32x4;

__device__ __forceinline__ unsigned short f2b(float f) {
  union { __hip_bfloat16 h; unsigned short u; } cv;
  cv.h = __float2bfloat16(f);
  return cv.u;
}

__global__ void zero_counts_k(int* counts) {
  if (threadIdx.x < NE) counts[threadIdx.x] = 0;
}

// 1024 threads/block: LDS histogram -> 8 global atomics per block.
__global__ void bin_rows_k(const int* __restrict__ yidx, int* __restrict__ counts,
                           int* __restrict__ bucket) {
  __shared__ int lcnt[NE];
  __shared__ int lbase[NE];
  int tid = threadIdx.x;
  if (tid < NE) lcnt[tid] = 0;
  __syncthreads();
  int b = blockIdx.x * blockDim.x + tid;
  int e = yidx[b];
  int pos = atomicAdd(&lcnt[e], 1);
  __syncthreads();
  if (tid < NE) lbase[tid] = atomicAdd(&counts[tid], lcnt[tid]);
  __syncthreads();
  bucket[e * NB + lbase[e] + pos] = b;
}

// [R][C] f32 -> [C][R] bf16, with XOR pre-swizzle of the output column so
// that a LINEAR copy into LDS yields the bank-conflict-free swizzled layout:
// short index col' = col ^ ((outrow & 7) << 3)   (byte ^= (row&7)<<4)
__global__ void transpose_cvt_k(const float* __restrict__ in,
                                unsigned short* __restrict__ out, int R, int C) {
  __shared__ float lt[32][33];
  int tpm = (R >> 5) * (C >> 5);
  int mat = blockIdx.x / tpm;
  int rem = blockIdx.x % tpm;
  int tcn = C >> 5;
  int tr = rem / tcn, tc = rem % tcn;
  const float* mi = in + (size_t)mat * R * C;
  unsigned short* mo = out + (size_t)mat * R * C;
  int r = threadIdx.x >> 5, c = threadIdx.x & 31;
#pragma unroll
  for (int i = 0; i < 4; ++i) {
    int rr = r + i * 8;
    lt[rr][c] = mi[(size_t)(tr * 32 + rr) * C + tc * 32 + c];
  }
  __syncthreads();
#pragma unroll
  for (int i = 0; i < 4; ++i) {
    int rr = r + i * 8;
    int orow = tc * 32 + rr;
    int ocol = (tr * 32 + c) ^ ((orow & 7) << 3);
    mo[(size_t)orow * R + ocol] = f2b(lt[c][rr]);
  }
}

// ---------------- Pass 1: H = relu(relu(X) @ W1 + b1) ----------------
// 256 blocks (e = blk>>5, j = blk&31), 512 thr = 8 waves. W1[e] (128 KB,
// swizzled) LDS-resident; each wave owns independent 16-row tiles.
__launch_bounds__(512, 2)
__global__ void pass1_k(const float* __restrict__ x, const float* __restrict__ b1,
                        const unsigned short* __restrict__ w1sw,
                        const int* __restrict__ counts, const int* __restrict__ bucket,
                        unsigned short* __restrict__ hbuf) {
  __shared__ unsigned short w1s[NS * ND];  // 131072 B
  int e = blockIdx.x >> 5;
  int j = blockIdx.x & 31;
  int cnt = counts[e];
  int tid = threadIdx.x;
  int w = tid >> 6, lane = tid & 63;
  int l15 = lane & 15, l4 = lane >> 4;

  // linear copy (global pre-swizzled -> LDS): 512 thr x 16 x 16B = 128 KB
  {
    const unsigned short* src = w1sw + (size_t)e * NS * ND + tid * 8;
#pragma unroll
    for (int i = 0; i < 16; ++i)
      *(u16x8*)&w1s[tid * 8 + i * 4096] = *(const u16x8*)(src + i * 4096);
  }
  __syncthreads();

  const float* b1e = b1 + e * NS;
  float bias[8];
#pragma unroll
  for (int nt = 0; nt < 8; ++nt) bias[nt] = b1e[nt * 16 + l15];

  const char* w1b = (const char*)w1s;
  const int ebase = e * NB;
  const float4 zero4 = make_float4(0.f, 0.f, 0.f, 0.f);

  for (int base = j * 128; base < cnt; base += 4096) {
    int r16 = base + w * 16;
    int ra = r16 + l15;
    int ridA = (ra < cnt) ? bucket[ebase + ra] : -1;
    int ridS[4];
#pragma unroll
    for (int r = 0; r < 4; ++r) {
      int rr = r16 + l4 * 4 + r;
      ridS[r] = (rr < cnt) ? bucket[ebase + rr] : -1;
    }
    const float* xrow = x + (size_t)ridA * ND;

    f32x4 acc[8];
#pragma unroll
    for (int i = 0; i < 8; ++i) acc[i] = (f32x4){0.f, 0.f, 0.f, 0.f};

    float4 f[8];
#pragma unroll
    for (int i = 0; i < 8; ++i) {
      int ks = i >> 1, half = (i & 1) * 4;
      f[i] = (ridA >= 0) ? *(const float4*)(xrow + ks * 32 + l4 * 8 + half) : zero4;
    }

#pragma unroll
    for (int kc = 0; kc < 4; ++kc) {
      bf16x8 a[4];
#pragma unroll
      for (int q = 0; q < 4; ++q) {
        float4 u = f[2 * q], v = f[2 * q + 1];
        bf16x8 t;
        t[0] = (short)f2b(fmaxf(u.x, 0.f)); t[1] = (short)f2b(fmaxf(u.y, 0.f));
        t[2] = (short)f2b(fmaxf(u.z, 0.f)); t[3] = (short)f2b(fmaxf(u.w, 0.f));
        t[4] = (short)f2b(fmaxf(v.x, 0.f)); t[5] = (short)f2b(fmaxf(v.y, 0.f));
        t[6] = (short)f2b(fmaxf(v.z, 0.f)); t[7] = (short)f2b(fmaxf(v.w, 0.f));
        a[q] = t;
      }
      if (kc < 3) {  // issue next K-chunk's loads early
#pragma unroll
        for (int i = 0; i < 8; ++i) {
          int ks = (kc + 1) * 4 + (i >> 1), half = (i & 1) * 4;
          f[i] = (ridA >= 0) ? *(const float4*)(xrow + ks * 32 + l4 * 8 + half) : zero4;
        }
      }
#pragma unroll
      for (int nt = 0; nt < 8; ++nt) {
        int n = nt * 16 + l15;
        int rowbyte = n * (ND * 2);
        int swz = (n & 7) << 4;
#pragma unroll
        for (int q = 0; q < 4; ++q) {
          int kbyte = (kc * 4 + q) * 64 + l4 * 16;
          bf16x8 bfr = *(const bf16x8*)(w1b + rowbyte + (kbyte ^ swz));
          acc[nt] = __builtin_amdgcn_mfma_f32_16x16x32_bf16(a[q], bfr, acc[nt], 0, 0, 0);
        }
      }
    }

    // H store (bf16), col = nt*16+l15, row = l4*4+r
#pragma unroll
    for (int nt = 0; nt < 8; ++nt) {
#pragma unroll
      for (int r = 0; r < 4; ++r) {
        if (ridS[r] >= 0)
          hbuf[(size_t)ridS[r] * NS + nt * 16 + l15] =
              f2b(fmaxf(acc[nt][r] + bias[nt], 0.f));
      }
    }
  }
}

// ---------------- Pass 2: out = x + (H @ W2 + b2) * z ----------------
__launch_bounds__(512, 2)
__global__ void pass2_k(const float* __restrict__ x, const float* __restrict__ z,
                        const float* __restrict__ b2,
                        const unsigned short* __restrict__ w2sw,
                        const int* __restrict__ counts, const int* __restrict__ bucket,
                        const unsigned short* __restrict__ hbuf,
                        float* __restrict__ out) {
  __shared__ unsigned short w2s[ND * NS];  // 131072 B
  int e = blockIdx.x >> 5;
  int j = blockIdx.x & 31;
  int cnt = counts[e];
  int tid = threadIdx.x;
  int w = tid >> 6, lane = tid & 63;
  int l15 = lane & 15, l4 = lane >> 4;

  {
    const unsigned short* src = w2sw + (size_t)e * ND * NS + tid * 8;
#pragma unroll
    for (int i = 0; i < 16; ++i)
      *(u16x8*)&w2s[tid * 8 + i * 4096] = *(const u16x8*)(src + i * 4096);
  }
  __syncthreads();

  const char* w2b = (const char*)w2s;
  const float* b2e = b2 + e * ND;
  const int ebase = e * NB;

  for (int base = j * 128; base < cnt; base += 4096) {
    int r16 = base + w * 16;
    int ra = r16 + l15;
    int ridA = (ra < cnt) ? bucket[ebase + ra] : -1;
    int ridS[4];
    float zS[4];
#pragma unroll
    for (int r = 0; r < 4; ++r) {
      int rr = r16 + l4 * 4 + r;
      ridS[r] = (rr < cnt) ? bucket[ebase + rr] : -1;
      zS[r] = (ridS[r] >= 0) ? z[ridS[r]] : 0.f;
    }

    bf16x8 ha[4];
    const unsigned short* hrow = hbuf + (size_t)ridA * NS;
#pragma unroll
    for (int kk = 0; kk < 4; ++kk) {
      if (ridA >= 0)
        ha[kk] = *(const bf16x8*)(hrow + kk * 32 + l4 * 8);
      else
        ha[kk] = (bf16x8)(short)0;
    }

#pragma unroll
    for (int dc = 0; dc < 4; ++dc) {
      f32x4 acc[8];
#pragma unroll
      for (int i = 0; i < 8; ++i) acc[i] = (f32x4){0.f, 0.f, 0.f, 0.f};
#pragma unroll
      for (int nt = 0; nt < 8; ++nt) {
        int n = dc * 128 + nt * 16 + l15;
        int rowbyte = n * (NS * 2);
        int swz = (n & 7) << 4;
#pragma unroll
        for (int kk = 0; kk < 4; ++kk) {
          int kbyte = kk * 64 + l4 * 16;
          bf16x8 bfr = *(const bf16x8*)(w2b + rowbyte + (kbyte ^ swz));
          acc[nt] = __builtin_amdgcn_mfma_f32_16x16x32_bf16(ha[kk], bfr, acc[nt], 0, 0, 0);
        }
      }
#pragma unroll
      for (int nt = 0; nt < 8; ++nt) {
        int d = dc * 128 + nt * 16 + l15;
        float bb = b2e[d];
#pragma unroll
        for (int r = 0; r < 4; ++r) {
          if (ridS[r] >= 0) {
            size_t off = (size_t)ridS[r] * ND + d;
            out[off] = x[off] + (acc[nt][r] + bb) * zS[r];
          }
        }
      }
    }
  }
}

extern "C" void kernel_launch(void* const* d_in, const int* in_sizes, int n_in,
                              void* d_out, int out_size, void* d_ws, size_t ws_size,
                              hipStream_t stream) {
  const float* x = (const float*)d_in[0];
  const int* yidx = (const int*)d_in[1];
  // d_in[2] = y_hard (unused by reference)
  const float* z = (const float*)d_in[3];
  const float* W1 = (const float*)d_in[4];
  const float* b1 = (const float*)d_in[5];
  const float* W2 = (const float*)d_in[6];
  const float* b2 = (const float*)d_in[7];
  float* out = (float*)d_out;

  char* ws = (char*)d_ws;
  int* counts = (int*)ws;                                   // 256 B
  int* bucket = (int*)(ws + 256);                           // 1 MB
  size_t off = 256 + (size_t)NE * NB * 4;
  unsigned short* w1sw = (unsigned short*)(ws + off);       // 1 MB
  off += (size_t)NE * NS * ND * 2;
  unsigned short* w2sw = (unsigned short*)(ws + off);       // 1 MB
  off += (size_t)NE * ND * NS * 2;
  unsigned short* hbuf = (unsigned short*)(ws + off);       // 8 MB

  zero_counts_k<<<1, 64, 0, stream>>>(counts);
  bin_rows_k<<<NB / 1024, 1024, 0, stream>>>(yidx, counts, bucket);
  // W1 [E][D][S] -> [E][S][D] (pre-swizzled cols)
  transpose_cvt_k<<<NE * (ND / 32) * (NS / 32), 256, 0, stream>>>(W1, w1sw, ND, NS);
  // W2 [E][S][D] -> [E][D][S] (pre-swizzled cols)
  transpose_cvt_k<<<NE * (NS / 32) * (ND / 32), 256, 0, stream>>>(W2, w2sw, NS, ND);
  pass1_k<<<NE * 32, 512, 0, stream>>>(x, b1, w1sw, counts, bucket, hbuf);
  pass2_k<<<NE * 32, 512, 0, stream>>>(x, z, b2, w2sw, counts, bucket, hbuf, out);
}

// Round 6
// 134.101 us; speedup vs baseline: 2.0610x; 2.0610x over previous
//
#include <hip/hip_runtime.h>
#include <hip/hip_bf16.h>

#define NB 32768
#define ND 512
#define NS 128
#define NE 8
#define TM 16
#define NT_PER_E 512  // covers cnt up to 8192

typedef __attribute__((ext_vector_type(8))) short bf16x8;
typedef __attribute__((ext_vector_type(8))) unsigned short u16x8;
typedef __attribute__((ext_vector_type(4))) float f32x4;

__device__ __forceinline__ unsigned short f2b(float f) {
  union { __hip_bfloat16 h; unsigned short u; } cv;
  cv.h = __float2bfloat16(f);
  return cv.u;
}

__global__ void zero_counts_k(int* counts) {
  if (threadIdx.x < NE) counts[threadIdx.x] = 0;
}

// 1024 threads/block: LDS histogram -> 8 global atomics per block.
__global__ void bin_rows_k(const int* __restrict__ yidx, int* __restrict__ counts,
                           int* __restrict__ bucket) {
  __shared__ int lcnt[NE];
  __shared__ int lbase[NE];
  int tid = threadIdx.x;
  if (tid < NE) lcnt[tid] = 0;
  __syncthreads();
  int b = blockIdx.x * blockDim.x + tid;
  int e = yidx[b];
  int pos = atomicAdd(&lcnt[e], 1);
  __syncthreads();
  if (tid < NE) lbase[tid] = atomicAdd(&counts[tid], lcnt[tid]);
  __syncthreads();
  bucket[e * NB + lbase[e] + pos] = b;
}

// [R][C] f32 -> [C][R] bf16 per matrix; grid = nmat*(R/32)*(C/32), 256 thr
__global__ void transpose_cvt_k(const float* __restrict__ in,
                                unsigned short* __restrict__ out, int R, int C) {
  __shared__ float lt[32][33];
  int tpm = (R >> 5) * (C >> 5);
  int mat = blockIdx.x / tpm;
  int rem = blockIdx.x % tpm;
  int tcn = C >> 5;
  int tr = rem / tcn, tc = rem % tcn;
  const float* mi = in + (size_t)mat * R * C;
  unsigned short* mo = out + (size_t)mat * R * C;
  int r = threadIdx.x >> 5, c = threadIdx.x & 31;
#pragma unroll
  for (int i = 0; i < 4; ++i) {
    int rr = r + i * 8;
    lt[rr][c] = mi[(size_t)(tr * 32 + rr) * C + tc * 32 + c];
  }
  __syncthreads();
#pragma unroll
  for (int i = 0; i < 4; ++i) {
    int rr = r + i * 8;
    mo[(size_t)(tc * 32 + rr) * R + tr * 32 + c] = f2b(lt[c][rr]);
  }
}

// One block = 16 rows of one expert; 4 waves split COLUMNS (R3 structure).
// XCD-pinned: e = blockIdx.x & 7, so expert e's weights stay in XCD e's L2.
// Stage1: wave w computes H[16][w*32..+32), K=512 unrolled, W1 frags from L2
// with one-chunk-ahead prefetch. Stage2: wave w computes out cols [w*128..+128).
__launch_bounds__(256, 4)
__global__ void moe_k(const float* __restrict__ x, const float* __restrict__ z,
                      const float* __restrict__ b1, const float* __restrict__ b2,
                      const unsigned short* __restrict__ w1t,
                      const unsigned short* __restrict__ w2t,
                      const int* __restrict__ counts, const int* __restrict__ bucket,
                      float* __restrict__ out) {
  __shared__ unsigned short xt[TM][516];  // 1032B row ≡ 2 banks mod 32
  __shared__ unsigned short ht[TM][132];
  __shared__ int rowid[TM];
  __shared__ float zrow[TM];

  int e = blockIdx.x & 7;         // XCD pin
  int t = blockIdx.x >> 3;        // tile within expert
  int cnt = counts[e];
  if (t * TM >= cnt) return;      // uniform exit before any barrier
  int m = min(TM, cnt - t * TM);
  int tid = threadIdx.x;
  int w = tid >> 6, lane = tid & 63;
  int l15 = lane & 15, l4 = lane >> 4;
  const int ebase = e * NB + t * TM;

  if (tid < TM) {
    int rid = (tid < m) ? bucket[ebase + tid] : -1;
    rowid[tid] = rid;
    zrow[tid] = (rid >= 0) ? z[rid] : 0.f;
  }

  // ---- stage X tile: 16 threads/row, 32B/lane segments, batched loads ----
  {
    int srow = tid >> 4;          // 0..15
    int sc = tid & 15;            // 32B unit within row
    int srid = (srow < m) ? bucket[ebase + srow] : -1;
    const float* xrow = x + (size_t)srid * ND + sc * 8;
    const float4 zero4 = make_float4(0.f, 0.f, 0.f, 0.f);
    float4 u[4], v[4];
#pragma unroll
    for (int j = 0; j < 4; ++j) {
      u[j] = (srid >= 0) ? *(const float4*)(xrow + j * 128) : zero4;
      v[j] = (srid >= 0) ? *(const float4*)(xrow + j * 128 + 4) : zero4;
    }
#pragma unroll
    for (int j = 0; j < 4; ++j) {
      u16x8 pk;
      pk[0] = f2b(fmaxf(u[j].x, 0.f)); pk[1] = f2b(fmaxf(u[j].y, 0.f));
      pk[2] = f2b(fmaxf(u[j].z, 0.f)); pk[3] = f2b(fmaxf(u[j].w, 0.f));
      pk[4] = f2b(fmaxf(v[j].x, 0.f)); pk[5] = f2b(fmaxf(v[j].y, 0.f));
      pk[6] = f2b(fmaxf(v[j].z, 0.f)); pk[7] = f2b(fmaxf(v[j].w, 0.f));
      *(u16x8*)&xt[srow][sc * 8 + j * 128] = pk;
    }
  }
  __syncthreads();

  // ---------------- stage 1 (W1 frags from L2, prefetch ahead) ----------------
  const unsigned short* w1e = w1t + (size_t)e * NS * ND;
  const unsigned short* w1p0 = w1e + (size_t)(w * 32 + l15) * ND + l4 * 8;
  const unsigned short* w1p1 = w1p0 + (size_t)16 * ND;
  f32x4 acc0 = (f32x4){0.f, 0.f, 0.f, 0.f};
  f32x4 acc1 = (f32x4){0.f, 0.f, 0.f, 0.f};
  bf16x8 wc[4], wn[4];
  wc[0] = *(const bf16x8*)(w1p0);
  wc[1] = *(const bf16x8*)(w1p0 + 32);
  wc[2] = *(const bf16x8*)(w1p1);
  wc[3] = *(const bf16x8*)(w1p1 + 32);
#pragma unroll
  for (int c = 0; c < 8; ++c) {
    if (c < 7) {
      const unsigned short* p0 = w1p0 + (c + 1) * 64;
      const unsigned short* p1 = w1p1 + (c + 1) * 64;
      wn[0] = *(const bf16x8*)(p0);
      wn[1] = *(const bf16x8*)(p0 + 32);
      wn[2] = *(const bf16x8*)(p1);
      wn[3] = *(const bf16x8*)(p1 + 32);
    }
    bf16x8 a0 = *(const bf16x8*)&xt[l15][c * 64 + l4 * 8];
    bf16x8 a1 = *(const bf16x8*)&xt[l15][c * 64 + 32 + l4 * 8];
    acc0 = __builtin_amdgcn_mfma_f32_16x16x32_bf16(a0, wc[0], acc0, 0, 0, 0);
    acc0 = __builtin_amdgcn_mfma_f32_16x16x32_bf16(a1, wc[1], acc0, 0, 0, 0);
    acc1 = __builtin_amdgcn_mfma_f32_16x16x32_bf16(a0, wc[2], acc1, 0, 0, 0);
    acc1 = __builtin_amdgcn_mfma_f32_16x16x32_bf16(a1, wc[3], acc1, 0, 0, 0);
#pragma unroll
    for (int i = 0; i < 4; ++i) wc[i] = wn[i];
  }

  // H = relu(acc + b1) -> ht; wave-private columns
  {
    int s0 = w * 32 + l15;
    float bias0 = b1[e * NS + s0];
    float bias1 = b1[e * NS + s0 + 16];
#pragma unroll
    for (int r = 0; r < 4; ++r) {
      ht[l4 * 4 + r][s0] = f2b(fmaxf(acc0[r] + bias0, 0.f));
      ht[l4 * 4 + r][s0 + 16] = f2b(fmaxf(acc1[r] + bias1, 0.f));
    }
  }
  __syncthreads();

  // ---------------- stage 2 ----------------
  bf16x8 ha[4];
#pragma unroll
  for (int kk = 0; kk < 4; ++kk)
    ha[kk] = *(const bf16x8*)&ht[l15][kk * 32 + l4 * 8];

  int orow[4];
  float zr4[4];
#pragma unroll
  for (int r = 0; r < 4; ++r) {
    orow[r] = rowid[l4 * 4 + r];
    zr4[r] = zrow[l4 * 4 + r];
  }

  const unsigned short* w2e = w2t + (size_t)e * ND * NS;
  const unsigned short* w2p = w2e + (size_t)(w * 128 + l15) * NS + l4 * 8;
  f32x4 acc2[8];
#pragma unroll
  for (int i = 0; i < 8; ++i) acc2[i] = (f32x4){0.f, 0.f, 0.f, 0.f};
  bf16x8 fc[4], fn[4];
#pragma unroll
  for (int kk = 0; kk < 4; ++kk) fc[kk] = *(const bf16x8*)(w2p + kk * 32);
#pragma unroll
  for (int nt = 0; nt < 8; ++nt) {
    if (nt < 7) {
      const unsigned short* p = w2p + (size_t)(nt + 1) * 16 * NS;
#pragma unroll
      for (int kk = 0; kk < 4; ++kk) fn[kk] = *(const bf16x8*)(p + kk * 32);
    }
#pragma unroll
    for (int kk = 0; kk < 4; ++kk)
      acc2[nt] = __builtin_amdgcn_mfma_f32_16x16x32_bf16(ha[kk], fc[kk], acc2[nt], 0, 0, 0);
#pragma unroll
    for (int kk = 0; kk < 4; ++kk) fc[kk] = fn[kk];
  }

  // epilogue: out = x + (acc2 + b2) * z
#pragma unroll
  for (int nt = 0; nt < 8; ++nt) {
    int d = w * 128 + nt * 16 + l15;
    float bias = b2[e * ND + d];
#pragma unroll
    for (int r = 0; r < 4; ++r) {
      if (orow[r] >= 0) {
        size_t off = (size_t)orow[r] * ND + d;
        out[off] = x[off] + (acc2[nt][r] + bias) * zr4[r];
      }
    }
  }
}

extern "C" void kernel_launch(void* const* d_in, const int* in_sizes, int n_in,
                              void* d_out, int out_size, void* d_ws, size_t ws_size,
                              hipStream_t stream) {
  const float* x = (const float*)d_in[0];
  const int* yidx = (const int*)d_in[1];
  // d_in[2] = y_hard (unused by reference)
  const float* z = (const float*)d_in[3];
  const float* W1 = (const float*)d_in[4];
  const float* b1 = (const float*)d_in[5];
  const float* W2 = (const float*)d_in[6];
  const float* b2 = (const float*)d_in[7];
  float* out = (float*)d_out;

  char* ws = (char*)d_ws;
  int* counts = (int*)ws;                                              // 256 B
  int* bucket = (int*)(ws + 256);                                      // 1 MB
  unsigned short* w1t = (unsigned short*)(ws + 256 + (size_t)NE * NB * 4);
  unsigned short* w2t = (unsigned short*)(ws + 256 + (size_t)NE * NB * 4 +
                                          (size_t)NE * ND * NS * 2);

  zero_counts_k<<<1, 64, 0, stream>>>(counts);
  bin_rows_k<<<NB / 1024, 1024, 0, stream>>>(yidx, counts, bucket);
  // W1 [E][D][S] -> w1t [E][S][D]
  transpose_cvt_k<<<NE * (ND / 32) * (NS / 32), 256, 0, stream>>>(W1, w1t, ND, NS);
  // W2 [E][S][D] -> w2t [E][D][S]
  transpose_cvt_k<<<NE * (NS / 32) * (ND / 32), 256, 0, stream>>>(W2, w2t, NS, ND);
  moe_k<<<NE * NT_PER_E, 256, 0, stream>>>(x, z, b1, b2, w1t, w2t, counts, bucket, out);
}

// Round 7
// 117.255 us; speedup vs baseline: 2.3571x; 1.1437x over previous
//
#include <hip/hip_runtime.h>
#include <hip/hip_bf16.h>

#define NB 32768
#define ND 512
#define NS 128
#define NE 8

typedef __attribute__((ext_vector_type(8))) short bf16x8;
typedef __attribute__((ext_vector_type(8))) unsigned short u16x8;
typedef __attribute__((ext_vector_type(4))) float f32x4;

__device__ __forceinline__ unsigned short f2b(float f) {
  union { __hip_bfloat16 h; unsigned short u; } cv;
  cv.h = __float2bfloat16(f);
  return cv.u;
}

__device__ __forceinline__ u16x8 relu_cvt8(float4 a, float4 b) {
  u16x8 r;
  r[0] = f2b(fmaxf(a.x, 0.f)); r[1] = f2b(fmaxf(a.y, 0.f));
  r[2] = f2b(fmaxf(a.z, 0.f)); r[3] = f2b(fmaxf(a.w, 0.f));
  r[4] = f2b(fmaxf(b.x, 0.f)); r[5] = f2b(fmaxf(b.y, 0.f));
  r[6] = f2b(fmaxf(b.z, 0.f)); r[7] = f2b(fmaxf(b.w, 0.f));
  return r;
}

// lgkm-only barrier: global loads stay in flight across it.
__device__ __forceinline__ void barrier_lgkm() {
  asm volatile("s_waitcnt lgkmcnt(0)\n\ts_barrier" ::: "memory");
}

__global__ void zero_counts_k(int* counts) {
  if (threadIdx.x < NE) counts[threadIdx.x] = 0;
}

__global__ void bin_rows_k(const int* __restrict__ yidx, int* __restrict__ counts,
                           int* __restrict__ bucket) {
  __shared__ int lcnt[NE];
  __shared__ int lbase[NE];
  int tid = threadIdx.x;
  if (tid < NE) lcnt[tid] = 0;
  __syncthreads();
  int b = blockIdx.x * blockDim.x + tid;
  int e = yidx[b];
  int pos = atomicAdd(&lcnt[e], 1);
  __syncthreads();
  if (tid < NE) lbase[tid] = atomicAdd(&counts[tid], lcnt[tid]);
  __syncthreads();
  bucket[e * NB + lbase[e] + pos] = b;
}

// exclusive scan of counts padded to 32 rows
__global__ void offs_k(const int* __restrict__ counts, int* __restrict__ offs) {
  if (threadIdx.x == 0) {
    int acc = 0;
    for (int e = 0; e < NE; ++e) {
      offs[e] = acc;
      acc += (counts[e] + 31) & ~31;
    }
  }
}

// [R][C] f32 -> [C][R] bf16 per matrix; grid = nmat*(R/32)*(C/32), 256 thr
__global__ void transpose_cvt_k(const float* __restrict__ in,
                                unsigned short* __restrict__ out, int R, int C) {
  __shared__ float lt[32][33];
  int tpm = (R >> 5) * (C >> 5);
  int mat = blockIdx.x / tpm;
  int rem = blockIdx.x % tpm;
  int tcn = C >> 5;
  int tr = rem / tcn, tc = rem % tcn;
  const float* mi = in + (size_t)mat * R * C;
  unsigned short* mo = out + (size_t)mat * R * C;
  int r = threadIdx.x >> 5, c = threadIdx.x & 31;
#pragma unroll
  for (int i = 0; i < 4; ++i) {
    int rr = r + i * 8;
    lt[rr][c] = mi[(size_t)(tr * 32 + rr) * C + tc * 32 + c];
  }
  __syncthreads();
#pragma unroll
  for (int i = 0; i < 4; ++i) {
    int rr = r + i * 8;
    mo[(size_t)(tc * 32 + rr) * R + tr * 32 + c] = f2b(lt[c][rr]);
  }
}

// ---- Pass 1: H[packed] = relu(relu(X) @ W1 + b1), 32-row tiles ----
// grid 8*1024, 256 thr = 4 waves; wave w owns H cols [w*32, w*32+32).
// K chunked by 64; x + W1 chunks reg-staged, double-buffered, lgkm barriers.
__launch_bounds__(256, 3)
__global__ void moe1_k(const float* __restrict__ x, const float* __restrict__ b1,
                       const unsigned short* __restrict__ w1t,
                       const int* __restrict__ counts, const int* __restrict__ bucket,
                       const int* __restrict__ offs,
                       unsigned short* __restrict__ hbuf) {
  __shared__ unsigned short xt[2][32][72];   // 9216 B
  __shared__ unsigned short wt[2][128][72];  // 36864 B
  int e = blockIdx.x & 7;                    // XCD pin
  int t = blockIdx.x >> 3;
  int cnt = counts[e];
  if (t * 32 >= cnt) return;
  int hbase = offs[e] + t * 32;
  int tid = threadIdx.x;
  int w = tid >> 6, lane = tid & 63;
  int l15 = lane & 15, l4 = lane >> 4;

  // staging roles
  int xrow = tid >> 3, xseg = (tid & 7) * 8;  // 8 f32 per thread
  int pos = t * 32 + xrow;
  int xrid = (pos < cnt) ? bucket[e * NB + pos] : -1;
  const float* xp = x + (size_t)xrid * ND + xseg;
  int wrow = tid >> 1, wseg = (tid & 1) * 32;  // 32 shorts per thread
  const unsigned short* wp =
      w1t + (size_t)e * NS * ND + (size_t)wrow * ND + wseg;

  const float4 z4 = make_float4(0.f, 0.f, 0.f, 0.f);
  float4 xa, xb;
  u16x8 wv[4];

  // prologue: chunk 0
  xa = (xrid >= 0) ? *(const float4*)xp : z4;
  xb = (xrid >= 0) ? *(const float4*)(xp + 4) : z4;
#pragma unroll
  for (int j = 0; j < 4; ++j) wv[j] = *(const u16x8*)(wp + j * 8);
  *(u16x8*)&xt[0][xrow][xseg] = relu_cvt8(xa, xb);
#pragma unroll
  for (int j = 0; j < 4; ++j) *(u16x8*)&wt[0][wrow][wseg + j * 8] = wv[j];
  barrier_lgkm();

  f32x4 acc[2][2];
#pragma unroll
  for (int i = 0; i < 2; ++i)
#pragma unroll
    for (int j = 0; j < 2; ++j) acc[i][j] = (f32x4){0.f, 0.f, 0.f, 0.f};

#pragma unroll
  for (int c = 0; c < 8; ++c) {
    int buf = c & 1;
    if (c < 7) {  // issue next chunk's global loads early
      int off = (c + 1) * 64;
      xa = (xrid >= 0) ? *(const float4*)(xp + off) : z4;
      xb = (xrid >= 0) ? *(const float4*)(xp + off + 4) : z4;
#pragma unroll
      for (int j = 0; j < 4; ++j) wv[j] = *(const u16x8*)(wp + off + j * 8);
    }
    // MFMA on chunk c
#pragma unroll
    for (int rt = 0; rt < 2; ++rt) {
      bf16x8 a0 = *(const bf16x8*)&xt[buf][rt * 16 + l15][l4 * 8];
      bf16x8 a1 = *(const bf16x8*)&xt[buf][rt * 16 + l15][32 + l4 * 8];
#pragma unroll
      for (int ct = 0; ct < 2; ++ct) {
        int n = w * 32 + ct * 16 + l15;
        bf16x8 b0 = *(const bf16x8*)&wt[buf][n][l4 * 8];
        bf16x8 b1f = *(const bf16x8*)&wt[buf][n][32 + l4 * 8];
        acc[rt][ct] = __builtin_amdgcn_mfma_f32_16x16x32_bf16(a0, b0, acc[rt][ct], 0, 0, 0);
        acc[rt][ct] = __builtin_amdgcn_mfma_f32_16x16x32_bf16(a1, b1f, acc[rt][ct], 0, 0, 0);
      }
    }
    if (c < 7) {
      barrier_lgkm();  // all waves done reading buf^1's old contents
      *(u16x8*)&xt[buf ^ 1][xrow][xseg] = relu_cvt8(xa, xb);
#pragma unroll
      for (int j = 0; j < 4; ++j) *(u16x8*)&wt[buf ^ 1][wrow][wseg + j * 8] = wv[j];
      barrier_lgkm();
    }
  }

  // epilogue: H = relu(acc + b1) -> hbuf (bf16, packed rows incl. pads)
#pragma unroll
  for (int ct = 0; ct < 2; ++ct) {
    int col = w * 32 + ct * 16 + l15;
    float bias = b1[e * NS + col];
#pragma unroll
    for (int rt = 0; rt < 2; ++rt) {
#pragma unroll
      for (int r = 0; r < 4; ++r) {
        int hrow = hbase + rt * 16 + l4 * 4 + r;
        hbuf[(size_t)hrow * NS + col] = f2b(fmaxf(acc[rt][ct][r] + bias, 0.f));
      }
    }
  }
}

// ---- Pass 2: out = x + (H @ W2 + b2) * z, 16-row tiles ----
// grid 8*2048, 256 thr = 4 waves; per 64-col N-chunk wave w owns 16 cols.
__launch_bounds__(256, 4)
__global__ void moe2_k(const float* __restrict__ x, const float* __restrict__ z,
                       const float* __restrict__ b2,
                       const unsigned short* __restrict__ w2t,
                       const int* __restrict__ counts, const int* __restrict__ bucket,
                       const int* __restrict__ offs,
                       const unsigned short* __restrict__ hbuf,
                       float* __restrict__ out) {
  __shared__ unsigned short hs[16][136];     // 4352 B
  __shared__ unsigned short wt[2][64][136];  // 34816 B
  __shared__ int rowid[16];
  __shared__ float zrow[16];
  int e = blockIdx.x & 7;                    // XCD pin
  int t = blockIdx.x >> 3;
  int cnt = counts[e];
  if (t * 16 >= cnt) return;
  int hbase = offs[e] + t * 16;
  int tid = threadIdx.x;
  int w = tid >> 6, lane = tid & 63;
  int l15 = lane & 15, l4 = lane >> 4;

  if (tid < 16) {
    int pos = t * 16 + tid;
    int rid = (pos < cnt) ? bucket[e * NB + pos] : -1;
    rowid[tid] = rid;
    zrow[tid] = (rid >= 0) ? z[rid] : 0.f;
  }

  // stage H tile + W2 chunk 0
  {
    int hrow = tid >> 4, hseg = (tid & 15) * 8;
    u16x8 hv = *(const u16x8*)&hbuf[(size_t)(hbase + hrow) * NS + hseg];
    *(u16x8*)&hs[hrow][hseg] = hv;
  }
  int wrow = tid >> 2, wseg = (tid & 3) * 32;  // 32 shorts per thread
  const unsigned short* wp =
      w2t + (size_t)e * ND * NS + (size_t)wrow * NS + wseg;
  u16x8 wv[4];
#pragma unroll
  for (int j = 0; j < 4; ++j) wv[j] = *(const u16x8*)(wp + j * 8);
#pragma unroll
  for (int j = 0; j < 4; ++j) *(u16x8*)&wt[0][wrow][wseg + j * 8] = wv[j];
  barrier_lgkm();

  bf16x8 ha[4];
#pragma unroll
  for (int kk = 0; kk < 4; ++kk)
    ha[kk] = *(const bf16x8*)&hs[l15][kk * 32 + l4 * 8];

  int orow[4];
  float zr4[4];
#pragma unroll
  for (int r = 0; r < 4; ++r) {
    orow[r] = rowid[l4 * 4 + r];
    zr4[r] = zrow[l4 * 4 + r];
  }

#pragma unroll
  for (int nc = 0; nc < 8; ++nc) {
    int buf = nc & 1;
    if (nc < 7) {  // issue next W2 chunk loads early
      size_t off = (size_t)(nc + 1) * 64 * NS;
#pragma unroll
      for (int j = 0; j < 4; ++j) wv[j] = *(const u16x8*)(wp + off + j * 8);
    }
    int d = nc * 64 + w * 16 + l15;
    // issue x re-reads for this chunk's outputs early
    float xe[4];
#pragma unroll
    for (int r = 0; r < 4; ++r)
      xe[r] = (orow[r] >= 0) ? x[(size_t)orow[r] * ND + d] : 0.f;
    float bias = b2[e * ND + d];

    f32x4 acc = (f32x4){0.f, 0.f, 0.f, 0.f};
#pragma unroll
    for (int kk = 0; kk < 4; ++kk) {
      bf16x8 bfr = *(const bf16x8*)&wt[buf][w * 16 + l15][kk * 32 + l4 * 8];
      acc = __builtin_amdgcn_mfma_f32_16x16x32_bf16(ha[kk], bfr, acc, 0, 0, 0);
    }
#pragma unroll
    for (int r = 0; r < 4; ++r) {
      if (orow[r] >= 0)
        out[(size_t)orow[r] * ND + d] = xe[r] + (acc[r] + bias) * zr4[r];
    }
    if (nc < 7) {
      barrier_lgkm();
#pragma unroll
      for (int j = 0; j < 4; ++j) *(u16x8*)&wt[buf ^ 1][wrow][wseg + j * 8] = wv[j];
      barrier_lgkm();
    }
  }
}

extern "C" void kernel_launch(void* const* d_in, const int* in_sizes, int n_in,
                              void* d_out, int out_size, void* d_ws, size_t ws_size,
                              hipStream_t stream) {
  const float* x = (const float*)d_in[0];
  const int* yidx = (const int*)d_in[1];
  // d_in[2] = y_hard (unused by reference)
  const float* z = (const float*)d_in[3];
  const float* W1 = (const float*)d_in[4];
  const float* b1 = (const float*)d_in[5];
  const float* W2 = (const float*)d_in[6];
  const float* b2 = (const float*)d_in[7];
  float* out = (float*)d_out;

  char* ws = (char*)d_ws;
  int* counts = (int*)ws;                     // 32 B
  int* offs = (int*)(ws + 64);                // 32 B
  int* bucket = (int*)(ws + 256);             // 1 MB
  size_t off = 256 + (size_t)NE * NB * 4;
  unsigned short* w1t = (unsigned short*)(ws + off);  // 1 MB
  off += (size_t)NE * NS * ND * 2;
  unsigned short* w2t = (unsigned short*)(ws + off);  // 1 MB
  off += (size_t)NE * ND * NS * 2;
  unsigned short* hbuf = (unsigned short*)(ws + off); // 8.5 MB

  zero_counts_k<<<1, 64, 0, stream>>>(counts);
  bin_rows_k<<<NB / 1024, 1024, 0, stream>>>(yidx, counts, bucket);
  offs_k<<<1, 64, 0, stream>>>(counts, offs);
  // W1 [E][D][S] -> w1t [E][S][D]
  transpose_cvt_k<<<NE * (ND / 32) * (NS / 32), 256, 0, stream>>>(W1, w1t, ND, NS);
  // W2 [E][S][D] -> w2t [E][D][S]
  transpose_cvt_k<<<NE * (NS / 32) * (ND / 32), 256, 0, stream>>>(W2, w2t, NS, ND);
  moe1_k<<<NE * (NB / 32), 256, 0, stream>>>(x, b1, w1t, counts, bucket, offs, hbuf);
  moe2_k<<<NE * (NB / 16), 256, 0, stream>>>(x, z, b2, w2t, counts, bucket, offs, hbuf, out);
}